// Round 3
// baseline (2200.398 us; speedup 1.0000x reference)
//
#include <hip/hip_runtime.h>

constexpr int NROWS  = 131072;
constexpr int LDIM   = 300;
constexpr int KDIM   = 600;
constexpr int NPAD   = 320;
constexpr int KGRP   = 76;                  // 608 / 8
constexpr int WT_ELEMS = KGRP * NPAD * 8;   // 194560 bf16 = 389120 B
constexpr int ROWS_PER_BLK = 32;
constexpr int NBLKS  = NROWS / ROWS_PER_BLK; // 4096 blocks of 64 threads
constexpr int KSTEPS = 38;                  // 608 / 16
constexpr size_t ACC_OFF = 389632;          // accum floats, after wt (16B aligned)

typedef __bf16 bf16x8 __attribute__((ext_vector_type(8)));
typedef float  f32x16 __attribute__((ext_vector_type(16)));

__device__ __forceinline__ unsigned short f2bf(float f) {
    unsigned u = __float_as_uint(f);
    u += 0x7fffu + ((u >> 16) & 1u);
    return (unsigned short)(u >> 16);
}

// ---- kernel 1: W1 -> bf16 fragment layout [kg][n][j]; also zero accum ----
__global__ void prep_w1(const float* __restrict__ w1, unsigned short* __restrict__ wt,
                        float* __restrict__ accum) {
    if (blockIdx.x == 0 && threadIdx.x < 8) accum[threadIdx.x] = 0.f;
    int idx = blockIdx.x * 256 + threadIdx.x;
    if (idx >= WT_ELEMS) return;
    int j    = idx & 7;
    int rest = idx >> 3;
    int n    = rest % NPAD;
    int kg   = rest / NPAD;
    int k    = kg * 8 + j;
    float v = 0.f;
    if (k < KDIM && n < LDIM) v = w1[k * LDIM + n];
    wt[idx] = f2bf(v);
}

// ---- kernel 2: barrier-free fused GEMM + epilogue (1 wave per block) ----
__global__ void main_kernel(const float* __restrict__ sbj, const float* __restrict__ obj,
                            const float* __restrict__ rlts,
                            const float* __restrict__ spa_w, const float* __restrict__ spa_b,
                            const float* __restrict__ b1, const float* __restrict__ w2,
                            const float* __restrict__ b2,
                            const unsigned short* __restrict__ wt,
                            float* __restrict__ out_scores, float* __restrict__ accum) {
    __shared__ float lanpart[ROWS_PER_BLK];

    const int lane = threadIdx.x;          // 0..63
    const int l31  = lane & 31;
    const int l5   = lane >> 5;
    const int row0 = blockIdx.x * ROWS_PER_BLK;
    const int arow = row0 + l31;           // this lane's A row

    const float* sbjrow = sbj + (size_t)arow * LDIM;
    const float* objrow = obj + (size_t)arow * LDIM;

    f32x16 acc[10];
    #pragma unroll
    for (int ct = 0; ct < 10; ++ct) acc[ct] = (f32x16)(0.f);

    float4 Apre[2][2];
    bf16x8 Bpre[2][10];

    auto loadA = [&](int kt, float4* A) {
        #pragma unroll
        for (int c = 0; c < 2; ++c) {
            const int k = kt * 16 + l5 * 8 + c * 4;   // 4-aligned; 300 % 4 == 0 -> no straddle
            // for k >= 600 the B-side is zero, so value is irrelevant; just keep the
            // address valid (dummy read of sbj row start)
            const float* p = (k < LDIM) ? (sbjrow + k)
                           : (k < KDIM) ? (objrow + (k - LDIM))
                           : sbjrow;
            A[c] = *(const float4*)p;
        }
    };
    auto loadB = [&](int kt, bf16x8* B) {
        const int kg = kt * 2 + l5;                   // 8-k group index
        const unsigned short* base = wt + ((size_t)kg * NPAD + l31) * 8;
        #pragma unroll
        for (int ct = 0; ct < 10; ++ct)
            B[ct] = *(const bf16x8*)(base + ct * 32 * 8);   // imm offset ct*512B
    };

    loadB(0, Bpre[0]);
    loadA(0, Apre[0]);
    loadA(1, Apre[1]);

    #pragma unroll 2
    for (int kt = 0; kt < KSTEPS; ++kt) {
        const int cur = kt & 1, nxt = cur ^ 1;
        if (kt + 1 < KSTEPS) loadB(kt + 1, Bpre[nxt]);      // L2, distance 1
        // consume A(kt) (issued 2 iters ago; older than B(kt) -> no extra wait)
        bf16x8 af;
        af[0] = (__bf16)fmaxf(Apre[cur][0].x, 0.f);
        af[1] = (__bf16)fmaxf(Apre[cur][0].y, 0.f);
        af[2] = (__bf16)fmaxf(Apre[cur][0].z, 0.f);
        af[3] = (__bf16)fmaxf(Apre[cur][0].w, 0.f);
        af[4] = (__bf16)fmaxf(Apre[cur][1].x, 0.f);
        af[5] = (__bf16)fmaxf(Apre[cur][1].y, 0.f);
        af[6] = (__bf16)fmaxf(Apre[cur][1].z, 0.f);
        af[7] = (__bf16)fmaxf(Apre[cur][1].w, 0.f);
        if (kt + 2 < KSTEPS) loadA(kt + 2, Apre[cur]);      // HBM, distance 2 (issued AFTER B)
        #pragma unroll
        for (int ct = 0; ct < 10; ++ct)
            acc[ct] = __builtin_amdgcn_mfma_f32_32x32x16_bf16(af, Bpre[cur][ct], acc[ct], 0, 0, 0);
    }

    // ---- epilogue: bias + relu + dot with w2 over 320 cols ----
    float pr[16];
    #pragma unroll
    for (int r = 0; r < 16; ++r) pr[r] = 0.f;

    #pragma unroll
    for (int ct = 0; ct < 10; ++ct) {
        const int n = ct * 32 + l31;
        const bool valid = (n < LDIM);
        const float b1n = valid ? b1[n] : 0.f;
        const float w2n = valid ? w2[n] : 0.f;
        #pragma unroll
        for (int r = 0; r < 16; ++r) {
            float h = fmaxf(acc[ct][r] + b1n, 0.f);
            pr[r] = fmaf(h, w2n, pr[r]);
        }
    }
    // allreduce over the 32 col-lanes
    #pragma unroll
    for (int off = 1; off < 32; off <<= 1)
        #pragma unroll
        for (int r = 0; r < 16; ++r)
            pr[r] += __shfl_xor(pr[r], off, 64);

    // C/D layout (m74/m101): row = (r&3) + 8*(r>>2) + 4*l5
    if (l31 == 0) {
        #pragma unroll
        for (int r = 0; r < 16; ++r)
            lanpart[(r & 3) + 8 * (r >> 2) + 4 * l5] = pr[r];
    }
    __syncthreads();

    // ---- per-row: box features, sigmoid, loss terms ----
    float s_loss = 0.f, s_cp = 0.f, s_cn = 0.f, s_pr = 0.f, s_nr = 0.f;
    if (lane < ROWS_PER_BLK) {
        const int g = row0 + lane;
        const float lan = lanpart[lane] + b2[0];
        const float* rr = rlts + (size_t)g * 15;
        const float label = rr[4];
        const float sx1 = rr[5],  sy1 = rr[6],  sx2 = rr[7],  sy2 = rr[8];
        const float ox1 = rr[10], oy1 = rr[11], ox2 = rr[12], oy2 = rr[13];
        const float sw = sx2 - sx1, sh = sy2 - sy1, ow = ox2 - ox1, oh = oy2 - oy1;
        float bs = spa_w[0] * ((sx1 - ox1) / sw)
                 + spa_w[1] * ((sy1 - oy1) / sh)
                 + spa_w[2] * logf(sw / ow)
                 + spa_w[3] * logf(sh / oh)
                 + spa_w[4] * ((ox1 - sx1) / ow)
                 + spa_w[5] * ((oy1 - sy1) / oh)
                 + spa_w[6] * logf(ow / sw)
                 + spa_w[7] * logf(oh / sh)
                 + spa_b[0];
        const float z = lan + bs;
        const float s = 1.f / (1.f + expf(-z));
        out_scores[g] = s;
        const float ls = fmaxf(logf(fminf(fmaxf(s, 1e-12f), 1.f)), -100.f);
        const float l1 = fmaxf(logf(fminf(fmaxf(1.f - s, 1e-12f), 1.f)), -100.f);
        const bool ys = label > 0.f;
        s_loss = ys ? ls : l1;
        s_cp   = ys ? 1.f : 0.f;
        s_cn   = ys ? 0.f : 1.f;
        s_pr   = (!ys && s >= 0.5f) ? 1.f : 0.f;
        s_nr   = (ys && s < 0.5f)  ? 1.f : 0.f;
    }
    #pragma unroll
    for (int off = 1; off < 64; off <<= 1) {
        s_loss += __shfl_xor(s_loss, off, 64);
        s_cp   += __shfl_xor(s_cp, off, 64);
        s_cn   += __shfl_xor(s_cn, off, 64);
        s_pr   += __shfl_xor(s_pr, off, 64);
        s_nr   += __shfl_xor(s_nr, off, 64);
    }
    if (lane == 0) {
        atomicAdd(&accum[0], s_loss);
        atomicAdd(&accum[1], s_cp);
        atomicAdd(&accum[2], s_cn);
        atomicAdd(&accum[3], s_pr);
        atomicAdd(&accum[4], s_nr);
    }
}

// ---- kernel 3: finalize scalars ----
__global__ void finalize(const float* __restrict__ accum, float* __restrict__ out) {
    if (threadIdx.x == 0) {
        const float t0 = accum[0], t1 = accum[1], t2 = accum[2], t3 = accum[3], t4 = accum[4];
        out[NROWS + 0] = -t0 / (float)NROWS;      // loss
        out[NROWS + 1] = t3 / t1;                 // recall_pos
        out[NROWS + 2] = t4 / t2;                 // recall_neg
        out[NROWS + 3] = (t3 + t4) / (t1 + t2);   // recall_all
    }
}

extern "C" void kernel_launch(void* const* d_in, const int* in_sizes, int n_in,
                              void* d_out, int out_size, void* d_ws, size_t ws_size,
                              hipStream_t stream) {
    const float* sbj   = (const float*)d_in[0];
    const float* obj   = (const float*)d_in[1];
    const float* rlts  = (const float*)d_in[2];
    const float* spa_w = (const float*)d_in[3];
    const float* spa_b = (const float*)d_in[4];
    const float* w1    = (const float*)d_in[5];
    const float* b1    = (const float*)d_in[6];
    const float* w2    = (const float*)d_in[7];
    const float* b2    = (const float*)d_in[8];
    float* out = (float*)d_out;

    unsigned short* wt = (unsigned short*)d_ws;
    float* accum = (float*)((char*)d_ws + ACC_OFF);

    prep_w1<<<(WT_ELEMS + 255) / 256, 256, 0, stream>>>(w1, wt, accum);
    main_kernel<<<NBLKS, 64, 0, stream>>>(sbj, obj, rlts, spa_w, spa_b, b1, w2, b2, wt, out, accum);
    finalize<<<1, 64, 0, stream>>>(accum, out);
}

// Round 4
// 618.023 us; speedup vs baseline: 3.5604x; 3.5604x over previous
//
#include <hip/hip_runtime.h>

constexpr int NROWS  = 131072;
constexpr int LDIM   = 300;
constexpr int KDIM   = 600;
constexpr int NPAD   = 320;
constexpr int KGRP   = 76;                  // 608 / 8
constexpr int WT_ELEMS = KGRP * NPAD * 8;   // 194560 bf16 = 389120 B
constexpr int ROWS_PER_BLK = 32;
constexpr int NBLKS  = NROWS / ROWS_PER_BLK; // 4096 blocks of 64 threads
constexpr int KSTEPS = 38;                  // 608 / 16
constexpr size_t ACC_OFF = 389632;          // accum floats, after wt (16B aligned)

typedef __bf16 bf16x8 __attribute__((ext_vector_type(8)));
typedef float  f32x16 __attribute__((ext_vector_type(16)));

__device__ __forceinline__ unsigned short f2bf(float f) {
    unsigned u = __float_as_uint(f);
    u += 0x7fffu + ((u >> 16) & 1u);
    return (unsigned short)(u >> 16);
}

// ---- kernel 1: W1 -> bf16 fragment layout [kg][n][j]; also zero accum ----
__global__ void prep_w1(const float* __restrict__ w1, unsigned short* __restrict__ wt,
                        float* __restrict__ accum) {
    if (blockIdx.x == 0 && threadIdx.x < 8) accum[threadIdx.x] = 0.f;
    int idx = blockIdx.x * 256 + threadIdx.x;
    if (idx >= WT_ELEMS) return;
    int j    = idx & 7;
    int rest = idx >> 3;
    int n    = rest % NPAD;
    int kg   = rest / NPAD;
    int k    = kg * 8 + j;
    float v = 0.f;
    if (k < KDIM && n < LDIM) v = w1[k * LDIM + n];
    wt[idx] = f2bf(v);
}

// ---- kernel 2: barrier-free fused GEMM + epilogue (1 wave per block) ----
// __launch_bounds__(64,1) is the round-3 spill fix: without it the compiler
// assumed 1024-thr blocks -> 64-VGPR cap -> 18KB/thread scratch -> 7.9 GB HBM.
__launch_bounds__(64, 1)
__global__ void main_kernel(const float* __restrict__ sbj, const float* __restrict__ obj,
                            const float* __restrict__ rlts,
                            const float* __restrict__ spa_w, const float* __restrict__ spa_b,
                            const float* __restrict__ b1, const float* __restrict__ w2,
                            const float* __restrict__ b2,
                            const unsigned short* __restrict__ wt,
                            float* __restrict__ out_scores, float* __restrict__ accum) {
    __shared__ float lanpart[ROWS_PER_BLK];

    const int lane = threadIdx.x;          // 0..63
    const int l31  = lane & 31;
    const int l5   = lane >> 5;
    const int row0 = blockIdx.x * ROWS_PER_BLK;
    const int arow = row0 + l31;           // this lane's A row

    const float* sbjrow = sbj + (size_t)arow * LDIM;
    const float* objrow = obj + (size_t)arow * LDIM;

    f32x16 acc[10];                        // 160 regs -> AGPRs
    #pragma unroll
    for (int ct = 0; ct < 10; ++ct) acc[ct] = (f32x16)(0.f);

    float4 Apre[4][2];                     // 32 VGPRs, prefetch distance 4 (HBM)
    bf16x8 Bpre[3][10];                    // 120 VGPRs, prefetch distance 2 (L2)

    auto loadA = [&](int kt, float4* A) {
        #pragma unroll
        for (int c = 0; c < 2; ++c) {
            const int k = kt * 16 + l5 * 8 + c * 4;   // 4-aligned; 300 % 4 == 0 -> no straddle
            const float* p = (k < LDIM) ? (sbjrow + k)
                           : (k < KDIM) ? (objrow + (k - LDIM))
                           : sbjrow;                   // k>=600: B side is zero, value unused
            A[c] = *(const float4*)p;
        }
    };
    auto loadB = [&](int kt, bf16x8* B) {
        const int kg = kt * 2 + l5;                   // 8-k group index
        const unsigned short* base = wt + ((size_t)kg * NPAD + l31) * 8;
        #pragma unroll
        for (int ct = 0; ct < 10; ++ct)
            B[ct] = *(const bf16x8*)(base + ct * 32 * 8);   // imm offset ct*512B
    };

    // prologue
    loadB(0, Bpre[0]);
    loadB(1, Bpre[1]);
    loadA(0, Apre[0]);
    loadA(1, Apre[1]);
    loadA(2, Apre[2]);
    loadA(3, Apre[3]);

    #pragma unroll
    for (int kt = 0; kt < KSTEPS; ++kt) {
        if (kt + 2 < KSTEPS) loadB(kt + 2, Bpre[(kt + 2) % 3]);   // L2, dist 2
        // consume A(kt) (oldest outstanding -> wait drains nothing younger)
        float4* Ac = Apre[kt & 3];
        bf16x8 af;
        af[0] = (__bf16)fmaxf(Ac[0].x, 0.f);
        af[1] = (__bf16)fmaxf(Ac[0].y, 0.f);
        af[2] = (__bf16)fmaxf(Ac[0].z, 0.f);
        af[3] = (__bf16)fmaxf(Ac[0].w, 0.f);
        af[4] = (__bf16)fmaxf(Ac[1].x, 0.f);
        af[5] = (__bf16)fmaxf(Ac[1].y, 0.f);
        af[6] = (__bf16)fmaxf(Ac[1].z, 0.f);
        af[7] = (__bf16)fmaxf(Ac[1].w, 0.f);
        if (kt + 4 < KSTEPS) loadA(kt + 4, Apre[kt & 3]);         // HBM, dist 4
        #pragma unroll
        for (int ct = 0; ct < 10; ++ct)
            acc[ct] = __builtin_amdgcn_mfma_f32_32x32x16_bf16(af, Bpre[kt % 3][ct], acc[ct], 0, 0, 0);
    }

    // ---- epilogue: bias + relu + dot with w2 over 320 cols ----
    float pr[16];
    #pragma unroll
    for (int r = 0; r < 16; ++r) pr[r] = 0.f;

    #pragma unroll
    for (int ct = 0; ct < 10; ++ct) {
        const int n = ct * 32 + l31;
        const bool valid = (n < LDIM);
        const float b1n = valid ? b1[n] : 0.f;
        const float w2n = valid ? w2[n] : 0.f;
        #pragma unroll
        for (int r = 0; r < 16; ++r) {
            float h = fmaxf(acc[ct][r] + b1n, 0.f);
            pr[r] = fmaf(h, w2n, pr[r]);
        }
    }
    // allreduce over the 32 col-lanes
    #pragma unroll
    for (int off = 1; off < 32; off <<= 1)
        #pragma unroll
        for (int r = 0; r < 16; ++r)
            pr[r] += __shfl_xor(pr[r], off, 64);

    // C/D layout (m74/m101): row = (r&3) + 8*(r>>2) + 4*l5
    if (l31 == 0) {
        #pragma unroll
        for (int r = 0; r < 16; ++r)
            lanpart[(r & 3) + 8 * (r >> 2) + 4 * l5] = pr[r];
    }
    __syncthreads();

    // ---- per-row: box features, sigmoid, loss terms ----
    float s_loss = 0.f, s_cp = 0.f, s_cn = 0.f, s_pr = 0.f, s_nr = 0.f;
    if (lane < ROWS_PER_BLK) {
        const int g = row0 + lane;
        const float lan = lanpart[lane] + b2[0];
        const float* rr = rlts + (size_t)g * 15;
        const float label = rr[4];
        const float sx1 = rr[5],  sy1 = rr[6],  sx2 = rr[7],  sy2 = rr[8];
        const float ox1 = rr[10], oy1 = rr[11], ox2 = rr[12], oy2 = rr[13];
        const float sw = sx2 - sx1, sh = sy2 - sy1, ow = ox2 - ox1, oh = oy2 - oy1;
        float bs = spa_w[0] * ((sx1 - ox1) / sw)
                 + spa_w[1] * ((sy1 - oy1) / sh)
                 + spa_w[2] * logf(sw / ow)
                 + spa_w[3] * logf(sh / oh)
                 + spa_w[4] * ((ox1 - sx1) / ow)
                 + spa_w[5] * ((oy1 - sy1) / oh)
                 + spa_w[6] * logf(ow / sw)
                 + spa_w[7] * logf(oh / sh)
                 + spa_b[0];
        const float z = lan + bs;
        const float s = 1.f / (1.f + expf(-z));
        out_scores[g] = s;
        const float ls = fmaxf(logf(fminf(fmaxf(s, 1e-12f), 1.f)), -100.f);
        const float l1 = fmaxf(logf(fminf(fmaxf(1.f - s, 1e-12f), 1.f)), -100.f);
        const bool ys = label > 0.f;
        s_loss = ys ? ls : l1;
        s_cp   = ys ? 1.f : 0.f;
        s_cn   = ys ? 0.f : 1.f;
        s_pr   = (!ys && s >= 0.5f) ? 1.f : 0.f;
        s_nr   = (ys && s < 0.5f)  ? 1.f : 0.f;
    }
    #pragma unroll
    for (int off = 1; off < 64; off <<= 1) {
        s_loss += __shfl_xor(s_loss, off, 64);
        s_cp   += __shfl_xor(s_cp, off, 64);
        s_cn   += __shfl_xor(s_cn, off, 64);
        s_pr   += __shfl_xor(s_pr, off, 64);
        s_nr   += __shfl_xor(s_nr, off, 64);
    }
    if (lane == 0) {
        atomicAdd(&accum[0], s_loss);
        atomicAdd(&accum[1], s_cp);
        atomicAdd(&accum[2], s_cn);
        atomicAdd(&accum[3], s_pr);
        atomicAdd(&accum[4], s_nr);
    }
}

// ---- kernel 3: finalize scalars ----
__global__ void finalize(const float* __restrict__ accum, float* __restrict__ out) {
    if (threadIdx.x == 0) {
        const float t0 = accum[0], t1 = accum[1], t2 = accum[2], t3 = accum[3], t4 = accum[4];
        out[NROWS + 0] = -t0 / (float)NROWS;      // loss
        out[NROWS + 1] = t3 / t1;                 // recall_pos
        out[NROWS + 2] = t4 / t2;                 // recall_neg
        out[NROWS + 3] = (t3 + t4) / (t1 + t2);   // recall_all
    }
}

extern "C" void kernel_launch(void* const* d_in, const int* in_sizes, int n_in,
                              void* d_out, int out_size, void* d_ws, size_t ws_size,
                              hipStream_t stream) {
    const float* sbj   = (const float*)d_in[0];
    const float* obj   = (const float*)d_in[1];
    const float* rlts  = (const float*)d_in[2];
    const float* spa_w = (const float*)d_in[3];
    const float* spa_b = (const float*)d_in[4];
    const float* w1    = (const float*)d_in[5];
    const float* b1    = (const float*)d_in[6];
    const float* w2    = (const float*)d_in[7];
    const float* b2    = (const float*)d_in[8];
    float* out = (float*)d_out;

    unsigned short* wt = (unsigned short*)d_ws;
    float* accum = (float*)((char*)d_ws + ACC_OFF);

    prep_w1<<<(WT_ELEMS + 255) / 256, 256, 0, stream>>>(w1, wt, accum);
    main_kernel<<<NBLKS, 64, 0, stream>>>(sbj, obj, rlts, spa_w, spa_b, b1, w2, b2, wt, out, accum);
    finalize<<<1, 64, 0, stream>>>(accum, out);
}